// Round 4
// baseline (2351.108 us; speedup 1.0000x reference)
//
#include <hip/hip_runtime.h>
#include <stdint.h>

#define GAS __attribute__((address_space(1)))
#define LAS __attribute__((address_space(3)))

typedef __attribute__((ext_vector_type(8))) short bf16x8;
typedef __attribute__((ext_vector_type(4))) float f32x4;

static constexpr int NB = 8192;    // batch
static constexpr int DD = 768;     // model dim (K)
static constexpr int FF = 32768;   // latent dim (N)
static constexpr int TK = 32;      // top-k
static constexpr int RUNC = 64;    // refined candidate cap per row
static constexpr int CAP = 1024;   // raw survivor cap per row
static constexpr int NS2 = 256;    // partial-sum slots for mean(W^2)

__device__ __forceinline__ ushort f2bf(float f) {
    unsigned x = __float_as_uint(f);
    unsigned r = (x + 0x7FFFu + ((x >> 16) & 1u)) >> 16;
    return (ushort)r;
}
__device__ __forceinline__ ushort sortkey(ushort u) {
    return (u & 0x8000u) ? (ushort)(u ^ 0xFFFFu) : (ushort)(u | 0x8000u);
}
__device__ __forceinline__ float bf2f(ushort u) {
    return __uint_as_float(((unsigned)u) << 16);
}
__device__ __forceinline__ void gload_lds16(const void* g, void* l) {
    __builtin_amdgcn_global_load_lds((const GAS unsigned int*)g,
                                     (LAS unsigned int*)l, 16, 0, 0);
}

// ---------------- prep: x_bf16 = bf16(x - pre_bias) ----------------
__global__ __launch_bounds__(256) void prep_x_k(const float* __restrict__ x,
                                                const float* __restrict__ pb,
                                                ushort* __restrict__ x16) {
    const int n4 = NB * DD / 4;
    for (int i = blockIdx.x * 256 + threadIdx.x; i < n4; i += gridDim.x * 256) {
        float4 v = ((const float4*)x)[i];
        float4 p = ((const float4*)pb)[i % (DD / 4)];
        ushort4 o;
        o.x = f2bf(v.x - p.x); o.y = f2bf(v.y - p.y);
        o.z = f2bf(v.z - p.z); o.w = f2bf(v.w - p.w);
        ((ushort4*)x16)[i] = o;
    }
}

// ------------- prep: transpose W_enc [D,F] -> Wt [F,D] (bf16 + f32) + sum(W^2) -------------
__global__ __launch_bounds__(256) void prep_w_k(const float* __restrict__ W,
                                                ushort* __restrict__ Wt16,
                                                float* __restrict__ Wt32,
                                                float* __restrict__ s2part) {
    __shared__ float tile[32][33];
    int f0 = blockIdx.x * 32, d0 = blockIdx.y * 32;
    int tx = threadIdx.x & 31, ty = threadIdx.x >> 5;  // ty 0..7
    float ss = 0.f;
#pragma unroll
    for (int q = 0; q < 4; q++) {
        int dl = ty + q * 8;
        float v = W[(size_t)(d0 + dl) * FF + f0 + tx];
        tile[dl][tx] = v;
        ss += v * v;
    }
    // wave-reduce ss, one atomic per wave into spread partials
#pragma unroll
    for (int o = 32; o >= 1; o >>= 1) ss += __shfl_down(ss, o);
    if ((threadIdx.x & 63) == 0) {
        int slot = (blockIdx.x * 97 + blockIdx.y * 13 + (threadIdx.x >> 6)) & (NS2 - 1);
        atomicAdd(&s2part[slot], ss);
    }
    __syncthreads();
#pragma unroll
    for (int q = 0; q < 4; q++) {
        int fl = ty + q * 8;
        float v = tile[tx][fl];
        size_t o = (size_t)(f0 + fl) * DD + d0 + tx;
        Wt16[o] = f2bf(v);
        if (Wt32) Wt32[o] = v;
    }
}

// ---------------- per-row threshold: tau[b] = 2.25 * sqrt(mean(W^2)) * ||x_b - pb|| ----------------
__global__ __launch_bounds__(256) void rn_k(const float* __restrict__ x,
                                            const float* __restrict__ pb,
                                            const float* __restrict__ s2part,
                                            float* __restrict__ tau) {
    int t = threadIdx.x, l = t & 63, w = t >> 6;
    __shared__ float wsum[4];
    __shared__ float s2m;
    float p = s2part[t];  // NS2 == 256
#pragma unroll
    for (int o = 32; o >= 1; o >>= 1) p += __shfl_down(p, o);
    if (l == 0) wsum[w] = p;
    __syncthreads();
    if (t == 0) s2m = (wsum[0] + wsum[1] + wsum[2] + wsum[3]) / ((float)DD * (float)FF);
    __syncthreads();
    int row = blockIdx.x * 4 + w;
    float ss = 0.f;
#pragma unroll
    for (int q = 0; q < 12; q++) {
        int d = l + 64 * q;
        float v = x[(size_t)row * DD + d] - pb[d];
        ss += v * v;
    }
#pragma unroll
    for (int o = 32; o >= 1; o >>= 1) ss += __shfl_down(ss, o);
    if (l == 0) tau[row] = 2.25f * sqrtf(s2m * ss);
}

// ---------------- bf16 MFMA GEMM with fused threshold filter (no latent materialization) ----------------
// 128x128 tile, BK=64, 4 waves (2x2), each wave 64x64 via 4x4 frags of 16x16x32.
// Epilogue: v = acc + lbias; if v >= tau[row], append (key<<16 | (32767-f)) to cand[row].
__global__ __launch_bounds__(256) void gemm_k(const ushort* __restrict__ A,
                                              const ushort* __restrict__ Bt,
                                              const float* __restrict__ lbias,
                                              const float* __restrict__ tau,
                                              unsigned* __restrict__ cand,
                                              unsigned* __restrict__ ccnt) {
    __shared__ __align__(16) char smem[32768];
    char* As = smem;
    char* Bs = smem + 16384;

    const int nwg = 64 * 256;       // 16384
    int cpx = nwg >> 3;
    int bid = (int)blockIdx.x;
    int wg = (bid & 7) * cpx + (bid >> 3);   // bijective XCD swizzle
    int mt = wg >> 8, nt = wg & 255;
    int m0 = mt << 7, n0l = nt << 7;

    int t = threadIdx.x, l = t & 63;
    int w = t >> 6, wm = w >> 1, wn = w & 1;

    int rs = t >> 3, cs = t & 7;
    const ushort* ga = A + (size_t)(m0 + rs) * DD + cs * 8;
    const ushort* gb = Bt + (size_t)(n0l + rs) * DD + cs * 8;
    char* lA = As + t * 16;
    char* lB = Bs + t * 16;

    f32x4 acc[4][4] = {};
    int k0b = (l >> 4) << 4;

    for (int kt = 0; kt < DD; kt += 64) {
#pragma unroll
        for (int i = 0; i < 4; i++) {
            gload_lds16(ga + kt + (size_t)(i * 32) * DD, lA + i * 4096);
            gload_lds16(gb + kt + (size_t)(i * 32) * DD, lB + i * 4096);
        }
        asm volatile("s_waitcnt vmcnt(0)" ::: "memory");
        __syncthreads();
#pragma unroll
        for (int ks = 0; ks < 2; ks++) {
            bf16x8 af[4], bfr[4];
#pragma unroll
            for (int i = 0; i < 4; i++) {
                int rA = (wm << 6) + (i << 4) + (l & 15);
                int rB = (wn << 6) + (i << 4) + (l & 15);
                af[i]  = *(const bf16x8*)(As + rA * 128 + (ks << 6) + k0b);
                bfr[i] = *(const bf16x8*)(Bs + rB * 128 + (ks << 6) + k0b);
            }
#pragma unroll
            for (int mi = 0; mi < 4; mi++)
#pragma unroll
                for (int ni = 0; ni < 4; ni++)
                    acc[mi][ni] = __builtin_amdgcn_mfma_f32_16x16x32_bf16(
                        af[mi], bfr[ni], acc[mi][ni], 0, 0, 0);
        }
        __syncthreads();
    }

    // epilogue: C/D map col=lane&15, row=(lane>>4)*4+j
    float taur[4][4];
#pragma unroll
    for (int mi = 0; mi < 4; mi++)
#pragma unroll
        for (int j = 0; j < 4; j++)
            taur[mi][j] = tau[m0 + (wm << 6) + (mi << 4) + ((l >> 4) << 2) + j];
#pragma unroll
    for (int ni = 0; ni < 4; ni++) {
        int f = n0l + (wn << 6) + (ni << 4) + (l & 15);
        float lbv = lbias[f];
#pragma unroll
        for (int mi = 0; mi < 4; mi++) {
            f32x4 v4 = acc[mi][ni];
#pragma unroll
            for (int j = 0; j < 4; j++) {
                float v = v4[j] + lbv;
                if (v >= taur[mi][j]) {
                    int r = m0 + (wm << 6) + (mi << 4) + ((l >> 4) << 2) + j;
                    unsigned pos = atomicAdd(&ccnt[r], 1u);
                    if (pos < CAP)
                        cand[(size_t)r * CAP + pos] =
                            ((unsigned)sortkey(f2bf(v)) << 16) | (unsigned)(32767 - f);
                }
            }
        }
    }
}

// ---------------- per-row: sort survivors, keep top-64 by key; flag pathological rows ----------------
__global__ __launch_bounds__(256) void select2_k(const unsigned* __restrict__ cand,
                                                 const unsigned* __restrict__ ccnt,
                                                 unsigned* __restrict__ flagv,
                                                 int* __restrict__ ridx,
                                                 int* __restrict__ runcnt) {
    int b = blockIdx.x, t = threadIdx.x;
    unsigned cnt = ccnt[b];
    int bad = (cnt < 48u || cnt > (unsigned)CAP);
    if (t == 0) { flagv[b] = bad; if (bad) runcnt[b] = 0; }
    if (bad) return;
    __shared__ unsigned srt[CAP];
    for (int i = t; i < CAP; i += 256)
        srt[i] = (i < (int)cnt) ? cand[(size_t)b * CAP + i] : 0u;
    __syncthreads();
    for (int k = 2; k <= CAP; k <<= 1) {
        for (int j = k >> 1; j > 0; j >>= 1) {
#pragma unroll
            for (int q = 0; q < CAP / 256; q++) {
                int i = t + q * 256;
                int ixj = i ^ j;
                if (ixj > i) {
                    unsigned a = srt[i], c2 = srt[ixj];
                    bool sw = ((i & k) == 0) ? (a < c2) : (a > c2);
                    if (sw) { srt[i] = c2; srt[ixj] = a; }
                }
            }
            __syncthreads();
        }
    }
    int nc = (int)cnt < RUNC ? (int)cnt : RUNC;
    if (t < nc) ridx[(size_t)b * RUNC + t] = 32767 - (int)(srt[t] & 0xFFFFu);
    if (t == 0) runcnt[b] = nc;
}

// ---------------- exact fallback for flagged rows (expected: zero rows) ----------------
__global__ __launch_bounds__(256) void fb_k(const unsigned* __restrict__ flagv,
                                            const float* __restrict__ x,
                                            const float* __restrict__ pb,
                                            const ushort* __restrict__ Wt16,
                                            const float* __restrict__ lb,
                                            int* __restrict__ ridx,
                                            int* __restrict__ runcnt) {
    int b = blockIdx.x;
    if (!flagv[b]) return;
    int t = threadIdx.x;
    __shared__ float xs[DD];
    __shared__ unsigned hist[256];
    __shared__ int s_cb, s_cum, s_T, s_pos;
    for (int i = t; i < DD; i += 256) xs[i] = x[(size_t)b * DD + i] - pb[i];
    hist[t] = 0;
    if (t == 0) s_pos = 0;
    __syncthreads();
    // pass 1: coarse histogram of recomputed keys
    for (int f = t; f < FF; f += 256) {
        const ushort* wr = Wt16 + (size_t)f * DD;
        float s = 0.f;
        for (int d = 0; d < DD; d++) s += xs[d] * bf2f(wr[d]);
        ushort k = sortkey(f2bf(s + lb[f]));
        atomicAdd(&hist[k >> 8], 1u);
    }
    __syncthreads();
    if (t == 0) {
        int cum = 0, cb = 0;
        for (int i = 255; i >= 0; i--) {
            if (cum + (int)hist[i] >= 48) { cb = i; break; }
            cum += (int)hist[i];
        }
        s_cb = cb; s_cum = cum;
    }
    __syncthreads();
    int cb = s_cb;
    hist[t] = 0;
    __syncthreads();
    // pass 2: fine histogram within coarse bin
    for (int f = t; f < FF; f += 256) {
        const ushort* wr = Wt16 + (size_t)f * DD;
        float s = 0.f;
        for (int d = 0; d < DD; d++) s += xs[d] * bf2f(wr[d]);
        ushort k = sortkey(f2bf(s + lb[f]));
        if ((int)(k >> 8) == cb) atomicAdd(&hist[k & 0xFF], 1u);
    }
    __syncthreads();
    if (t == 0) {
        int cum = s_cum, T = cb << 8;
        for (int fb = 255; fb >= 0; fb--) {
            if (cum + (int)hist[fb] >= 48) { T = (cb << 8) | fb; break; }
            cum += (int)hist[fb];
        }
        s_T = T;
    }
    __syncthreads();
    unsigned T = (unsigned)s_T;
    // pass 3: emit all >= T (cap RUNC)
    for (int f = t; f < FF; f += 256) {
        const ushort* wr = Wt16 + (size_t)f * DD;
        float s = 0.f;
        for (int d = 0; d < DD; d++) s += xs[d] * bf2f(wr[d]);
        ushort k = sortkey(f2bf(s + lb[f]));
        if (k >= T) {
            int p = atomicAdd(&s_pos, 1);
            if (p < RUNC) ridx[(size_t)b * RUNC + p] = f;
        }
    }
    __syncthreads();
    if (t == 0) runcnt[b] = s_pos < RUNC ? s_pos : RUNC;
}

// ---------------- refine: fp64 re-dot of candidates, exact top-32 ----------------
__global__ __launch_bounds__(256) void refine_k(const float* __restrict__ x,
                                                const float* __restrict__ pb,
                                                const float* __restrict__ We,
                                                const float* __restrict__ Wt32,
                                                const float* __restrict__ lb,
                                                const int* __restrict__ runidx,
                                                const int* __restrict__ runcnt,
                                                int use_t,
                                                int* __restrict__ sidx,
                                                float* __restrict__ sval) {
    int b = blockIdx.x, t = threadIdx.x, l = t & 63, w = t >> 6;
    __shared__ float xs[DD];
    __shared__ int ci[RUNC];
    __shared__ float cv[RUNC];
    for (int i = t; i < DD; i += 256) xs[i] = x[(size_t)b * DD + i] - pb[i];
    int c = runcnt[b]; if (c > RUNC) c = RUNC;
    if (t < RUNC) cv[t] = -1e30f;
    if (t < c) ci[t] = runidx[(size_t)b * RUNC + t];
    __syncthreads();
    for (int j = w; j < c; j += 4) {
        int f = ci[j];
        double s = 0.0;
        if (use_t) {
            const float* wr = Wt32 + (size_t)f * DD;
#pragma unroll
            for (int q = 0; q < 12; q++)
                s = fma((double)wr[l + 64 * q], (double)xs[l + 64 * q], s);
        } else {
#pragma unroll
            for (int q = 0; q < 12; q++)
                s = fma((double)We[(size_t)(l + 64 * q) * FF + f], (double)xs[l + 64 * q], s);
        }
#pragma unroll
        for (int o = 32; o >= 1; o >>= 1) s += __shfl_down(s, o);
        if (l == 0) cv[j] = (float)(s + (double)lb[f]);
    }
    __syncthreads();
    if (w == 0) {
        float v0 = cv[l];
        int i0 = (l < c) ? ci[l] : 0x7FFFFFFF;
        for (int sel = 0; sel < TK; sel++) {
            float bv = v0; int bi = i0;
#pragma unroll
            for (int o = 32; o >= 1; o >>= 1) {
                float ov = __shfl_xor(bv, o);
                int oi = __shfl_xor(bi, o);
                if (ov > bv || (ov == bv && oi < bi)) { bv = ov; bi = oi; }
            }
            if (i0 == bi) v0 = -1e30f;
            if (l == 0) {
                sidx[(size_t)b * TK + sel] = bi;
                sval[(size_t)b * TK + sel] = bv > 0.f ? bv : 0.f;
            }
        }
    }
}

// ---------------- decode ----------------
__global__ __launch_bounds__(192) void decode_k(const float* __restrict__ sval,
                                                const int* __restrict__ sidx,
                                                const float* __restrict__ Wd,
                                                const float* __restrict__ pb,
                                                float* __restrict__ out) {
    int b = blockIdx.x, t = threadIdx.x;
    __shared__ float sv[TK];
    __shared__ int si[TK];
    if (t < TK) { sv[t] = sval[(size_t)b * TK + t]; si[t] = sidx[(size_t)b * TK + t]; }
    __syncthreads();
    float4 acc = ((const float4*)pb)[t];
#pragma unroll 4
    for (int j = 0; j < TK; j++) {
        float v = sv[j];
        float4 wv = ((const float4*)(Wd + (size_t)si[j] * DD))[t];
        acc.x += v * wv.x; acc.y += v * wv.y;
        acc.z += v * wv.z; acc.w += v * wv.w;
    }
    ((float4*)out)[(size_t)b * (DD / 4) + t] = acc;
}

extern "C" void kernel_launch(void* const* d_in, const int* in_sizes, int n_in,
                              void* d_out, int out_size, void* d_ws, size_t ws_size,
                              hipStream_t stream) {
    const float* x  = (const float*)d_in[0];
    const float* pb = (const float*)d_in[1];
    const float* We = (const float*)d_in[2];
    const float* lb = (const float*)d_in[3];
    const float* Wd = (const float*)d_in[4];
    float* out = (float*)d_out;
    char* ws = (char*)d_ws;
    (void)in_sizes; (void)n_in; (void)out_size;

    const size_t SZ_X16  = (size_t)NB * DD * 2;        // 12.6 MB
    const size_t SZ_WT16 = (size_t)FF * DD * 2;        // 50.3 MB
    const size_t SZ_WT32 = (size_t)FF * DD * 4;        // 100.7 MB
    const size_t SZ_CAND = (size_t)NB * CAP * 4;       // 33.6 MB
    const size_t SZ_CTRL = (size_t)NB * 4 * 2 + NS2 * 4;  // ccnt + flag + s2part
    const size_t SZ_TAU  = (size_t)NB * 4;
    const size_t SZ_RIDX = (size_t)NB * RUNC * 4;
    const size_t SZ_RCNT = (size_t)NB * 4;
    const size_t SZ_SIDX = (size_t)NB * TK * 4;
    const size_t SZ_SVAL = (size_t)NB * TK * 4;

    size_t need_base = SZ_X16 + SZ_WT16 + SZ_CAND + SZ_CTRL + SZ_TAU +
                       SZ_RIDX + SZ_RCNT + SZ_SIDX + SZ_SVAL;
    int use_t = (ws_size >= need_base + SZ_WT32) ? 1 : 0;

    size_t off = 0;
    ushort* x16   = (ushort*)(ws + off); off += SZ_X16;
    ushort* Wt16  = (ushort*)(ws + off); off += SZ_WT16;
    float*  Wt32  = nullptr;
    if (use_t) { Wt32 = (float*)(ws + off); off += SZ_WT32; }
    unsigned* ccnt = (unsigned*)(ws + off);            // start of memset region
    char* ctrl0   = (char*)(ws + off); off += (size_t)NB * 4;
    unsigned* flagv = (unsigned*)(ws + off); off += (size_t)NB * 4;
    float* s2part = (float*)(ws + off); off += NS2 * 4;
    size_t ctrl_bytes = (size_t)((ws + off) - ctrl0);
    float* tau    = (float*)(ws + off); off += SZ_TAU;
    unsigned* cand = (unsigned*)(ws + off); off += SZ_CAND;
    int* ridx     = (int*)(ws + off); off += SZ_RIDX;
    int* rcnt     = (int*)(ws + off); off += SZ_RCNT;
    int* sidx     = (int*)(ws + off); off += SZ_SIDX;
    float* sval   = (float*)(ws + off); off += SZ_SVAL;

    hipMemsetAsync(ctrl0, 0, ctrl_bytes, stream);
    prep_x_k<<<2048, 256, 0, stream>>>(x, pb, x16);
    prep_w_k<<<dim3(FF / 32, DD / 32), 256, 0, stream>>>(We, Wt16, Wt32, s2part);
    rn_k<<<NB / 4, 256, 0, stream>>>(x, pb, s2part, tau);
    gemm_k<<<64 * 256, 256, 0, stream>>>(x16, Wt16, lb, tau, cand, ccnt);
    select2_k<<<NB, 256, 0, stream>>>(cand, ccnt, flagv, ridx, rcnt);
    fb_k<<<NB, 256, 0, stream>>>(flagv, x, pb, Wt16, lb, ridx, rcnt);
    refine_k<<<NB, 256, 0, stream>>>(x, pb, We, Wt32, lb, ridx, rcnt, use_t, sidx, sval);
    decode_k<<<NB, 192, 0, stream>>>(sval, sidx, Wd, pb, out);
}